// Round 13
// baseline (401.948 us; speedup 1.0000x reference)
//
#include <hip/hip_runtime.h>
#include <stdint.h>

#define T_DIM 8192
#define IN_DIM 1024
#define OUT_DIM 1024
#define M_DIM 128
#define SEG 64
#define NSEG (T_DIM / SEG)   // 128
#define CHUNK 2048           // fallback path only
#define KS_FB 4

typedef __bf16 bf16x8 __attribute__((ext_vector_type(8)));
typedef float f32x4 __attribute__((ext_vector_type(4)));

__device__ inline unsigned short f2bf(float f) {
  unsigned int u = __float_as_uint(f);
  unsigned int r = (u + 0x7fffu + ((u >> 16) & 1u)) >> 16;
  return (unsigned short)r;
}
__device__ inline float bf2f(unsigned short h) {
  return __uint_as_float(((unsigned int)h) << 16);
}
__device__ inline float sigm(float v) { return 1.f / (1.f + expf(-v)); }

// ---------------- fused prep: x->bf16, mix_w perm->bf16, Wgs cat, bias cat, gamma ----------------
#define N_X   8388608L
#define N_MIX 8388608L
#define N_WGS 2359296L
__global__ __launch_bounds__(256) void prep_kernel(
    const float* __restrict__ x, const float* __restrict__ mix_w,
    const float* __restrict__ gout_w, const float* __restrict__ skip_w,
    const float* __restrict__ pre_w, const float* __restrict__ gin_w,
    const float* __restrict__ gout_b, const float* __restrict__ skip_b,
    const float* __restrict__ pre_b, const float* __restrict__ gin_b,
    const float* __restrict__ a, const float* __restrict__ b,
    unsigned short* __restrict__ x_bf, unsigned short* __restrict__ Bmix,
    unsigned short* __restrict__ Wgs, float* __restrict__ bias_gs,
    float2* __restrict__ gam, float2* __restrict__ gamL) {
  const long total = N_X + N_MIX + N_WGS + 2304 + 4096;
  for (long i = (long)blockIdx.x * 256 + threadIdx.x; i < total;
       i += (long)gridDim.x * 256) {
    if (i < N_X) {
      x_bf[i] = f2bf(x[i]);
    } else if (i < N_X + N_MIX) {
      long j = i - N_X;
      long row = j >> 13;
      int k = (int)(j & 8191);
      int src = ((k >> 6) << 6) | ((k & 1) << 5) | ((k >> 1) & 31);
      Bmix[j] = f2bf(mix_w[(row << 13) + src]);
    } else if (i < N_X + N_MIX + N_WGS) {
      long j = i - N_X - N_MIX;
      int row = (int)(j >> 10), col = (int)(j & 1023);
      float v;
      if (row < 1024)       v = gout_w[row * 1024 + col];
      else if (row < 2048)  v = skip_w[(row - 1024) * 1024 + col];
      else if (row < 2176)  v = pre_w[(row - 2048) * 1024 + col];
      else                  v = gin_w[(row - 2176) * 1024 + col];
      Wgs[j] = f2bf(v);
    } else if (i < N_X + N_MIX + N_WGS + 2304) {
      int j = (int)(i - N_X - N_MIX - N_WGS);
      float v;
      if (j < 1024)      v = gout_b[j];
      else if (j < 2048) v = skip_b[j - 1024];
      else if (j < 2176) v = pre_b[j - 2048];
      else               v = gin_b[j - 2176];
      bias_gs[j] = v;
    } else {
      int tid = (int)(i - N_X - N_MIX - N_WGS - 2304);   // 0..4095
      int m = tid >> 5, c = tid & 31;
      double aa = fabs((double)a[m]);
      double ang = (double)b[c];
      double mag = exp(-aa);
      gam[tid] = make_float2((float)(mag * cos(ang)), (float)(mag * sin(ang)));
      double magL = exp(-aa * (double)SEG);
      double angL = ang * (double)SEG;
      gamL[tid] = make_float2((float)(magL * cos(angL)), (float)(magL * sin(angL)));
    }
  }
}

// ======== m97-style GEMM body (T2 swizzle, reg-diet for 4 blocks/CU) ========
#define GEMM_KLOOP(AP, BP, LDK)                                                        \
  for (int k0 = 0; k0 < kloop_end; k0 += 64) {                                         \
    _Pragma("unroll")                                                                  \
    for (int cc = 0; cc < 4; ++cc) {                                                   \
      __builtin_amdgcn_global_load_lds(                                                \
          (const __attribute__((address_space(1))) void*)(AP + k0 + (size_t)cc * 32 * (LDK)), \
          (__attribute__((address_space(3))) void*)(As + cc * 2048 + w * 512), 16, 0, 0);     \
      __builtin_amdgcn_global_load_lds(                                                \
          (const __attribute__((address_space(1))) void*)(BP + k0 + (size_t)cc * 32 * (LDK)), \
          (__attribute__((address_space(3))) void*)(Bs + cc * 2048 + w * 512), 16, 0, 0);     \
    }                                                                                  \
    __syncthreads();                                                                   \
    _Pragma("unroll")                                                                  \
    for (int kk = 0; kk < 2; ++kk) {                                                   \
      const int eb = kk ? e1 : e0;                                                     \
      const char* Bp = (const char*)Bpbase + eb;                                       \
      bf16x8 b0 = *(const bf16x8*)(Bp);                                                \
      bf16x8 b1 = *(const bf16x8*)(Bp + 2048);                                         \
      bf16x8 b2 = *(const bf16x8*)(Bp + 4096);                                         \
      bf16x8 b3 = *(const bf16x8*)(Bp + 6144);                                         \
      const char* Ap = (const char*)Apbase + eb;                                       \
      _Pragma("unroll")                                                                \
      for (int i = 0; i < 4; ++i) {                                                    \
        bf16x8 af = *(const bf16x8*)(Ap + i * 2048);                                   \
        acc[i][0] = __builtin_amdgcn_mfma_f32_16x16x32_bf16(af, b0, acc[i][0], 0, 0, 0);\
        acc[i][1] = __builtin_amdgcn_mfma_f32_16x16x32_bf16(af, b1, acc[i][1], 0, 0, 0);\
        acc[i][2] = __builtin_amdgcn_mfma_f32_16x16x32_bf16(af, b2, acc[i][2], 0, 0, 0);\
        acc[i][3] = __builtin_amdgcn_mfma_f32_16x16x32_bf16(af, b3, acc[i][3], 0, 0, 0);\
      }                                                                                \
    }                                                                                  \
    __syncthreads();                                                                   \
  }

#define GEMM_PREAMBLE                                                                  \
  const int tid = threadIdx.x;                                                         \
  const int lane = tid & 63, w = tid >> 6;                                             \
  const int wr = w >> 1, wc = w & 1;                                                   \
  f32x4 acc[4][4] = {};                                                                \
  const int srow = tid >> 3;                                                           \
  const int ksw = ((tid & 7) ^ (srow & 7)) * 8;                                        \
  const int l15 = lane & 15;                                                           \
  const int krd = (lane >> 4) * 8;                                                     \
  const int rsw = (lane & 7) << 3;                                                     \
  const int e0 = (krd ^ rsw) * 2;                                                      \
  const int e1 = ((32 + krd) ^ rsw) * 2;                                               \
  const unsigned short* Apbase = &As[(wr * 64 + l15) * 64];                            \
  const unsigned short* Bpbase = &Bs[(wc * 64 + l15) * 64];

// ---------------- merged gout/skip/pre/gin GEMM (m97 structure) ----------------
__global__ __launch_bounds__(256, 4) void gemm_gs_kernel(
    const unsigned short* __restrict__ A, const unsigned short* __restrict__ B,
    const float* __restrict__ bias, unsigned short* __restrict__ gs,
    float* __restrict__ tmp) {
  __shared__ __align__(16) unsigned short As[128 * 64];
  __shared__ __align__(16) unsigned short Bs[128 * 64];
  const int xcd = blockIdx.x & 7;
  const int idx = blockIdx.x >> 3;        // 0..143
  const int bn = idx % 18;
  const int bm = xcd * 8 + idx / 18;
  const int n0 = bn * 128, t0 = bm * 128;
  GEMM_PREAMBLE
  const unsigned short* Ab = A + (size_t)(t0 + srow) * 1024 + ksw;
  const unsigned short* Bb = B + (size_t)(n0 + srow) * 1024 + ksw;
  const int kloop_end = 1024;
  GEMM_KLOOP(Ab, Bb, 1024)

  const int rbase = t0 + wr * 64 + ((lane >> 4) * 4);
  const int cbase = n0 + wc * 64 + l15;
#pragma unroll
  for (int j = 0; j < 4; ++j) {
    const int col = cbase + j * 16;
    const float bv = bias[col];
#pragma unroll
    for (int i = 0; i < 4; ++i) {
#pragma unroll
      for (int r = 0; r < 4; ++r) {
        float v = acc[i][j][r] + bv;
        int row = rbase + i * 16 + r;
        if (col < 2048) gs[(size_t)row * 2048 + col] = f2bf(v);
        else            tmp[(size_t)row * 256 + (col - 2048)] = v;
      }
    }
  }
}

// ---------------- split-K mix GEMM: partials[ks][prows][1024] ----------------
// xcd_map=1 (main): 1024 blocks = exactly 4 blocks/CU; each XCD owns
// {ks=xcd>>2, 16-bm slice, all 8 bn}.  xcd_map=0 (fallback): bijective swizzle.
__global__ __launch_bounds__(256, 4) void gemm_splitk_kernel(
    const unsigned short* __restrict__ A, const unsigned short* __restrict__ B,
    float* __restrict__ partials, int nbm, int kslice, int prows, int xcd_map) {
  __shared__ __align__(16) unsigned short As[128 * 64];
  __shared__ __align__(16) unsigned short Bs[128 * 64];
  int bm, bn, ks;
  if (xcd_map) {
    const int xcd = blockIdx.x & 7;
    const int idx = blockIdx.x >> 3;      // 0..127
    ks = xcd >> 2;
    bm = (xcd & 3) * 16 + (idx >> 3);
    bn = idx & 7;
  } else {
    const int cpx = gridDim.x >> 3;
    const int wid = (blockIdx.x & 7) * cpx + (blockIdx.x >> 3);
    bm = wid % nbm;
    bn = (wid / nbm) & 7;
    ks = wid / (nbm * 8);
  }
  const int n0 = bn * 128, t0 = bm * 128;
  GEMM_PREAMBLE
  const unsigned short* Ab = A + (size_t)(t0 + srow) * 8192 + ks * kslice + ksw;
  const unsigned short* Bb = B + (size_t)(n0 + srow) * 8192 + ks * kslice + ksw;
  const int kloop_end = kslice;
  GEMM_KLOOP(Ab, Bb, 8192)

  float* Cp = partials + (size_t)ks * prows * 1024;
  const int rbase = t0 + wr * 64 + ((lane >> 4) * 4);
  const int cbase = n0 + wc * 64 + l15;
#pragma unroll
  for (int j = 0; j < 4; ++j) {
    const int col = cbase + j * 16;
#pragma unroll
    for (int i = 0; i < 4; ++i)
#pragma unroll
      for (int r = 0; r < 4; ++r)
        Cp[(size_t)(rbase + i * 16 + r) * 1024 + col] = acc[i][j][r];
  }
}

// fallback reduce
__global__ __launch_bounds__(256) void reduce_kernel(const f32x4* __restrict__ partials,
                                                     const f32x4* __restrict__ bias4,
                                                     f32x4* __restrict__ outc) {
  int i = blockIdx.x * 256 + threadIdx.x;
  const size_t stride = (size_t)CHUNK * 256;
  f32x4 s = partials[i];
#pragma unroll
  for (int p = 1; p < KS_FB; ++p) s += partials[(size_t)p * stride + i];
  s += bias4[i & 255];
  outc[i] = s;
}

// ================= parallel scan (gated computed inline from tmp_pg) =================
__device__ inline float gated_at(const float* __restrict__ tmp, int t, int m) {
  float p = tmp[t * 256 + m];
  float g = tmp[t * 256 + 128 + m];
  return p * sigm(g);
}

__global__ __launch_bounds__(256) void scan_p1_kernel(
    const float* __restrict__ tmp, const int* __restrict__ done,
    const float2* __restrict__ gam, const float2* __restrict__ gamL,
    float2* __restrict__ carryA, float2* __restrict__ carryB) {
  int gid = blockIdx.x * 256 + threadIdx.x;
  int seg = gid >> 12, tid = gid & 4095;
  int m = tid >> 5;
  float2 g = gam[tid];
  int t0 = seg * SEG;
  float sr = 0.f, si = 0.f, keep_all = 1.f;
  for (int tt = 0; tt < SEG; ++tt) {
    int t = t0 + tt;
    float xv = gated_at(tmp, t, m);
    bool d = done[t] != 0;
    float pr = d ? 0.f : sr;
    float pi = d ? 0.f : si;
    if (d) keep_all = 0.f;
    sr = fmaf(g.x, pr, fmaf(-g.y, pi, xv));
    si = fmaf(g.y, pr, g.x * pi);
  }
  carryB[(size_t)seg * 4096 + tid] = make_float2(sr, si);
  float2 gL = gamL[tid];
  carryA[(size_t)seg * 4096 + tid] = make_float2(keep_all * gL.x, keep_all * gL.y);
}

__global__ __launch_bounds__(256) void scan_p2_kernel(
    const float2* __restrict__ carryA, float2* __restrict__ carryB,
    const float* __restrict__ s0_re, const float* __restrict__ s0_im) {
  int tid = blockIdx.x * 256 + threadIdx.x;
  float sr = s0_re[tid], si = s0_im[tid];
  float2 A0 = carryA[tid], B0 = carryB[tid];
  for (int p = 0; p < NSEG; ++p) {
    size_t nidx = (size_t)(p + 1) * 4096 + tid;
    float2 A1, B1;
    if (p + 1 < NSEG) { A1 = carryA[nidx]; B1 = carryB[nidx]; }
    carryB[(size_t)p * 4096 + tid] = make_float2(sr, si);
    float nr = fmaf(A0.x, sr, fmaf(-A0.y, si, B0.x));
    float ni = fmaf(A0.y, sr, fmaf(A0.x, si, B0.y));
    sr = nr; si = ni;
    A0 = A1; B0 = B1;
  }
}

__global__ __launch_bounds__(256) void scan_p3_kernel(
    const float* __restrict__ tmp, const int* __restrict__ done,
    const float2* __restrict__ gam, const float2* __restrict__ segstart,
    float* __restrict__ out_states, int pair_mode,
    unsigned int* __restrict__ st_bf, int tbase) {
  int gid = blockIdx.x * 256 + threadIdx.x;
  int segl = gid >> 12, tid = gid & 4095;
  int m = tid >> 5;
  int seg = tbase / SEG + segl;
  float2 g = gam[tid];
  float2 s = segstart[(size_t)seg * 4096 + tid];
  float sr = s.x, si = s.y;
  int t0 = seg * SEG;
  for (int tt = 0; tt < SEG; ++tt) {
    int t = t0 + tt;
    float xv = gated_at(tmp, t, m);
    bool d = done[t] != 0;
    float pr = d ? 0.f : sr;
    float pi = d ? 0.f : si;
    sr = fmaf(g.x, pr, fmaf(-g.y, pi, xv));
    si = fmaf(g.y, pr, g.x * pi);
    if (pair_mode) {
      ((float2*)out_states)[(size_t)t * 4096 + tid] = make_float2(sr, si);
    } else {
      out_states[(size_t)t * 4096 + tid] = sr;
    }
    st_bf[(size_t)(t - tbase) * 4096 + tid] =
        (unsigned int)f2bf(sr) | ((unsigned int)f2bf(si) << 16);
  }
}

// ---------------- fused reduce + bias + LN + gates ----------------
__global__ __launch_bounds__(256) void ln_kernel(const float* __restrict__ partials, int nred,
                                                 const float* __restrict__ mixb,
                                                 const unsigned short* __restrict__ gs,
                                                 float* __restrict__ out) {
  const int t = blockIdx.x;
  const int tid = threadIdx.x;
  __shared__ float sm[8];
  const int o = tid * 4;
  f32x4 z;
  if (nred == 0) {
    z = *(const f32x4*)&out[(size_t)t * 1024 + o];
  } else {
    z = *(const f32x4*)&partials[(size_t)t * 1024 + o];
    for (int p = 1; p < nred; ++p)
      z += *(const f32x4*)&partials[(size_t)p * T_DIM * 1024 + (size_t)t * 1024 + o];
    z += *(const f32x4*)&mixb[o];
  }
  ushort4 gu = *(const ushort4*)&gs[(size_t)t * 2048 + o];
  ushort4 su = *(const ushort4*)&gs[(size_t)t * 2048 + 1024 + o];
  float g[4], sk[4], zg[4];
  g[0] = sigm(bf2f(gu.x)); g[1] = sigm(bf2f(gu.y));
  g[2] = sigm(bf2f(gu.z)); g[3] = sigm(bf2f(gu.w));
  sk[0] = bf2f(su.x); sk[1] = bf2f(su.y); sk[2] = bf2f(su.z); sk[3] = bf2f(su.w);
  float sum = 0.f;
#pragma unroll
  for (int j = 0; j < 4; ++j) { zg[j] = z[j] * g[j]; sum += zg[j]; }
#pragma unroll
  for (int off = 32; off > 0; off >>= 1) sum += __shfl_down(sum, off, 64);
  if ((tid & 63) == 0) sm[tid >> 6] = sum;
  __syncthreads();
  const float mu = (sm[0] + sm[1] + sm[2] + sm[3]) * (1.f / 1024.f);
  float sq = 0.f;
#pragma unroll
  for (int j = 0; j < 4; ++j) { float d = zg[j] - mu; sq += d * d; }
#pragma unroll
  for (int off = 32; off > 0; off >>= 1) sq += __shfl_down(sq, off, 64);
  if ((tid & 63) == 0) sm[4 + (tid >> 6)] = sq;
  __syncthreads();
  const float var = (sm[4] + sm[5] + sm[6] + sm[7]) * (1.f / 1024.f);
  const float rstd = 1.f / sqrtf(var + 1e-5f);
  f32x4 res;
#pragma unroll
  for (int j = 0; j < 4; ++j) res[j] = (zg[j] - mu) * rstd + sk[j] * (1.f - g[j]);
  *(f32x4*)&out[(size_t)t * 1024 + o] = res;
}

extern "C" void kernel_launch(void* const* d_in, const int* in_sizes, int n_in,
                              void* d_out, int out_size, void* d_ws, size_t ws_size,
                              hipStream_t stream) {
  const float* x      = (const float*)d_in[0];
  const int*   done   = (const int*)d_in[1];
  const float* s0_re  = (const float*)d_in[2];
  const float* s0_im  = (const float*)d_in[3];
  const float* a      = (const float*)d_in[4];
  const float* b      = (const float*)d_in[5];
  const float* pre_w  = (const float*)d_in[6];
  const float* pre_b  = (const float*)d_in[7];
  const float* gin_w  = (const float*)d_in[8];
  const float* gin_b  = (const float*)d_in[9];
  const float* gout_w = (const float*)d_in[10];
  const float* gout_b = (const float*)d_in[11];
  const float* skip_w = (const float*)d_in[12];
  const float* skip_b = (const float*)d_in[13];
  const float* mix_w  = (const float*)d_in[14];
  const float* mix_b  = (const float*)d_in[15];

  float* out_f = (float*)d_out;                               // [T][1024]
  float* states_f = out_f + (size_t)T_DIM * OUT_DIM;
  const int pair_mode = (out_size >= 75000000) ? 1 : 0;

  char* ws = (char*)d_ws;
  size_t off = 0;
  auto alloc = [&](size_t bytes) {
    void* p = ws + off;
    off = (off + bytes + 255) & ~(size_t)255;
    return p;
  };
  unsigned short* x_bf   = (unsigned short*)alloc((size_t)T_DIM * IN_DIM * 2);
  unsigned short* Bmix   = (unsigned short*)alloc((size_t)OUT_DIM * 8192 * 2);
  unsigned short* Wgs    = (unsigned short*)alloc((size_t)2304 * IN_DIM * 2);
  float* bias_gs         = (float*)alloc(2304 * 4);
  float* tmp_pg          = (float*)alloc((size_t)T_DIM * 256 * 4);
  float2* gam            = (float2*)alloc(4096 * 8);
  float2* gamL           = (float2*)alloc(4096 * 8);
  float2* carryA         = (float2*)alloc((size_t)NSEG * 4096 * 8);
  float2* carryB         = (float2*)alloc((size_t)NSEG * 4096 * 8);
  unsigned short* gs_o   = (unsigned short*)alloc((size_t)T_DIM * 2048 * 2);

  size_t need_main = off + (size_t)T_DIM * 8192 * 2 + (size_t)2 * T_DIM * 1024 * 4 + 1024;
  const int full_path = (ws_size == 0 || ws_size >= need_main) ? 1 : 0;

  dim3 blk(256);
  prep_kernel<<<2048, blk, 0, stream>>>(x, mix_w, gout_w, skip_w, pre_w, gin_w,
                                        gout_b, skip_b, pre_b, gin_b, a, b,
                                        x_bf, Bmix, Wgs, bias_gs, gam, gamL);

  gemm_gs_kernel<<<1152, blk, 0, stream>>>(x_bf, Wgs, bias_gs, gs_o, tmp_pg);

  scan_p1_kernel<<<NSEG * 16, blk, 0, stream>>>(tmp_pg, done, gam, gamL, carryA, carryB);
  scan_p2_kernel<<<16, blk, 0, stream>>>(carryA, carryB, s0_re, s0_im);

  if (full_path) {
    unsigned short* st_bf = (unsigned short*)alloc((size_t)T_DIM * 8192 * 2);
    float* partials       = (float*)alloc((size_t)2 * T_DIM * 1024 * 4);
    scan_p3_kernel<<<NSEG * 16, blk, 0, stream>>>(tmp_pg, done, gam, carryB,
                                                  states_f, pair_mode,
                                                  (unsigned int*)st_bf, 0);
    // ONE split-K GEMM: 1024 blocks = exactly 4 blocks/CU, single dispatch phase
    gemm_splitk_kernel<<<1024, blk, 0, stream>>>(st_bf, Bmix, partials,
                                                 64, 4096, T_DIM, 1);
    ln_kernel<<<T_DIM, blk, 0, stream>>>(partials, 2, mix_b, gs_o, out_f);
  } else {
    unsigned short* st_bf = (unsigned short*)alloc((size_t)CHUNK * 8192 * 2);
    float* partials       = (float*)alloc((size_t)KS_FB * CHUNK * 1024 * 4);
    for (int ch = 0; ch < T_DIM / CHUNK; ++ch) {
      int tbase = ch * CHUNK;
      scan_p3_kernel<<<(CHUNK / SEG) * 16, blk, 0, stream>>>(tmp_pg, done, gam, carryB,
                                                             states_f, pair_mode,
                                                             (unsigned int*)st_bf, tbase);
      gemm_splitk_kernel<<<8 * (CHUNK / 128) * KS_FB, blk, 0, stream>>>(
          st_bf, Bmix, partials, CHUNK / 128, 8192 / KS_FB, CHUNK, 0);
      reduce_kernel<<<CHUNK, blk, 0, stream>>>((const f32x4*)partials, (const f32x4*)mix_b,
                                               (f32x4*)(out_f + (size_t)tbase * OUT_DIM));
    }
    ln_kernel<<<T_DIM, blk, 0, stream>>>(nullptr, 0, mix_b, gs_o, out_f);
  }
  (void)n_in; (void)in_sizes;
}

// Round 14
// 360.323 us; speedup vs baseline: 1.1155x; 1.1155x over previous
//
#include <hip/hip_runtime.h>
#include <stdint.h>

#define T_DIM 8192
#define IN_DIM 1024
#define OUT_DIM 1024
#define M_DIM 128
#define SEG 64
#define NSEG (T_DIM / SEG)   // 128
#define CHUNK 2048           // fallback path only
#define KS_FB 4

typedef __bf16 bf16x8 __attribute__((ext_vector_type(8)));
typedef float f32x4 __attribute__((ext_vector_type(4)));

__device__ inline unsigned short f2bf(float f) {
  unsigned int u = __float_as_uint(f);
  unsigned int r = (u + 0x7fffu + ((u >> 16) & 1u)) >> 16;
  return (unsigned short)r;
}
__device__ inline float bf2f(unsigned short h) {
  return __uint_as_float(((unsigned int)h) << 16);
}
__device__ inline float sigm(float v) { return 1.f / (1.f + expf(-v)); }

// ---------------- fused prep ----------------
#define N_X   8388608L
#define N_MIX 8388608L
#define N_WGS 2359296L
__global__ __launch_bounds__(256) void prep_kernel(
    const float* __restrict__ x, const float* __restrict__ mix_w,
    const float* __restrict__ gout_w, const float* __restrict__ skip_w,
    const float* __restrict__ pre_w, const float* __restrict__ gin_w,
    const float* __restrict__ gout_b, const float* __restrict__ skip_b,
    const float* __restrict__ pre_b, const float* __restrict__ gin_b,
    const float* __restrict__ a, const float* __restrict__ b,
    unsigned short* __restrict__ x_bf, unsigned short* __restrict__ Bmix,
    unsigned short* __restrict__ Wgs, float* __restrict__ bias_gs,
    float2* __restrict__ gam, float2* __restrict__ gamL) {
  const long total = N_X + N_MIX + N_WGS + 2304 + 4096;
  for (long i = (long)blockIdx.x * 256 + threadIdx.x; i < total;
       i += (long)gridDim.x * 256) {
    if (i < N_X) {
      x_bf[i] = f2bf(x[i]);
    } else if (i < N_X + N_MIX) {
      long j = i - N_X;
      long row = j >> 13;
      int k = (int)(j & 8191);
      int src = ((k >> 6) << 6) | ((k & 1) << 5) | ((k >> 1) & 31);
      Bmix[j] = f2bf(mix_w[(row << 13) + src]);
    } else if (i < N_X + N_MIX + N_WGS) {
      long j = i - N_X - N_MIX;
      int row = (int)(j >> 10), col = (int)(j & 1023);
      float v;
      if (row < 1024)       v = gout_w[row * 1024 + col];
      else if (row < 2048)  v = skip_w[(row - 1024) * 1024 + col];
      else if (row < 2176)  v = pre_w[(row - 2048) * 1024 + col];
      else                  v = gin_w[(row - 2176) * 1024 + col];
      Wgs[j] = f2bf(v);
    } else if (i < N_X + N_MIX + N_WGS + 2304) {
      int j = (int)(i - N_X - N_MIX - N_WGS);
      float v;
      if (j < 1024)      v = gout_b[j];
      else if (j < 2048) v = skip_b[j - 1024];
      else if (j < 2176) v = pre_b[j - 2048];
      else               v = gin_b[j - 2176];
      bias_gs[j] = v;
    } else {
      int tid = (int)(i - N_X - N_MIX - N_WGS - 2304);   // 0..4095
      int m = tid >> 5, c = tid & 31;
      double aa = fabs((double)a[m]);
      double ang = (double)b[c];
      double mag = exp(-aa);
      gam[tid] = make_float2((float)(mag * cos(ang)), (float)(mag * sin(ang)));
      double magL = exp(-aa * (double)SEG);
      double angL = ang * (double)SEG;
      gamL[tid] = make_float2((float)(magL * cos(angL)), (float)(magL * sin(angL)));
    }
  }
}

// ======== m97-style GEMM body (gs GEMM + fallback) ========
#define GEMM_KLOOP(AP, BP, LDK)                                                        \
  for (int k0 = 0; k0 < kloop_end; k0 += 64) {                                         \
    _Pragma("unroll")                                                                  \
    for (int cc = 0; cc < 4; ++cc) {                                                   \
      __builtin_amdgcn_global_load_lds(                                                \
          (const __attribute__((address_space(1))) void*)(AP + k0 + (size_t)cc * 32 * (LDK)), \
          (__attribute__((address_space(3))) void*)(As + cc * 2048 + w * 512), 16, 0, 0);     \
      __builtin_amdgcn_global_load_lds(                                                \
          (const __attribute__((address_space(1))) void*)(BP + k0 + (size_t)cc * 32 * (LDK)), \
          (__attribute__((address_space(3))) void*)(Bs + cc * 2048 + w * 512), 16, 0, 0);     \
    }                                                                                  \
    __syncthreads();                                                                   \
    _Pragma("unroll")                                                                  \
    for (int kk = 0; kk < 2; ++kk) {                                                   \
      const int eb = kk ? e1 : e0;                                                     \
      const char* Bp = (const char*)Bpbase + eb;                                       \
      bf16x8 b0 = *(const bf16x8*)(Bp);                                                \
      bf16x8 b1 = *(const bf16x8*)(Bp + 2048);                                         \
      bf16x8 b2 = *(const bf16x8*)(Bp + 4096);                                         \
      bf16x8 b3 = *(const bf16x8*)(Bp + 6144);                                         \
      const char* Ap = (const char*)Apbase + eb;                                       \
      _Pragma("unroll")                                                                \
      for (int i = 0; i < 4; ++i) {                                                    \
        bf16x8 af = *(const bf16x8*)(Ap + i * 2048);                                   \
        acc[i][0] = __builtin_amdgcn_mfma_f32_16x16x32_bf16(af, b0, acc[i][0], 0, 0, 0);\
        acc[i][1] = __builtin_amdgcn_mfma_f32_16x16x32_bf16(af, b1, acc[i][1], 0, 0, 0);\
        acc[i][2] = __builtin_amdgcn_mfma_f32_16x16x32_bf16(af, b2, acc[i][2], 0, 0, 0);\
        acc[i][3] = __builtin_amdgcn_mfma_f32_16x16x32_bf16(af, b3, acc[i][3], 0, 0, 0);\
      }                                                                                \
    }                                                                                  \
    __syncthreads();                                                                   \
  }

#define GEMM_PREAMBLE                                                                  \
  const int tid = threadIdx.x;                                                         \
  const int lane = tid & 63, w = tid >> 6;                                             \
  const int wr = w >> 1, wc = w & 1;                                                   \
  f32x4 acc[4][4] = {};                                                                \
  const int srow = tid >> 3;                                                           \
  const int ksw = ((tid & 7) ^ (srow & 7)) * 8;                                        \
  const int l15 = lane & 15;                                                           \
  const int krd = (lane >> 4) * 8;                                                     \
  const int rsw = (lane & 7) << 3;                                                     \
  const int e0 = (krd ^ rsw) * 2;                                                      \
  const int e1 = ((32 + krd) ^ rsw) * 2;                                               \
  const unsigned short* Apbase = &As[(wr * 64 + l15) * 64];                            \
  const unsigned short* Bpbase = &Bs[(wc * 64 + l15) * 64];

// ---------------- merged gout/skip/pre/gin GEMM (m97 structure) ----------------
__global__ __launch_bounds__(256, 4) void gemm_gs_kernel(
    const unsigned short* __restrict__ A, const unsigned short* __restrict__ B,
    const float* __restrict__ bias, unsigned short* __restrict__ gs,
    float* __restrict__ tmp) {
  __shared__ __align__(16) unsigned short As[128 * 64];
  __shared__ __align__(16) unsigned short Bs[128 * 64];
  const int xcd = blockIdx.x & 7;
  const int idx = blockIdx.x >> 3;
  const int bn = idx % 18;
  const int bm = xcd * 8 + idx / 18;
  const int n0 = bn * 128, t0 = bm * 128;
  GEMM_PREAMBLE
  const unsigned short* Ab = A + (size_t)(t0 + srow) * 1024 + ksw;
  const unsigned short* Bb = B + (size_t)(n0 + srow) * 1024 + ksw;
  const int kloop_end = 1024;
  GEMM_KLOOP(Ab, Bb, 1024)

  const int rbase = t0 + wr * 64 + ((lane >> 4) * 4);
  const int cbase = n0 + wc * 64 + l15;
#pragma unroll
  for (int j = 0; j < 4; ++j) {
    const int col = cbase + j * 16;
    const float bv = bias[col];
#pragma unroll
    for (int i = 0; i < 4; ++i) {
#pragma unroll
      for (int r = 0; r < 4; ++r) {
        float v = acc[i][j][r] + bv;
        int row = rbase + i * 16 + r;
        if (col < 2048) gs[(size_t)row * 2048 + col] = f2bf(v);
        else            tmp[(size_t)row * 256 + (col - 2048)] = v;
      }
    }
  }
}

// ======== 256x256 fine 8-phase split-K mix GEMM (v4) ========
__global__ __launch_bounds__(512, 1) void gemm_mix256_kernel(
    const unsigned short* __restrict__ A, const unsigned short* __restrict__ B,
    float* __restrict__ partials) {
  __shared__ __align__(16) unsigned short As[3][256 * 64];   // 96 KB
  __shared__ __align__(16) unsigned short Bs[2][256 * 64];   // 64 KB
  const int xcd = blockIdx.x & 7;
  const int idx = blockIdx.x >> 3;        // 0..31
  const int ks = xcd >> 2;
  const int bm = (xcd & 3) * 8 + (idx >> 2);
  const int bn = idx & 3;
  const int t0 = bm * 256, n0 = bn * 256;
  const int tid = threadIdx.x;
  const int lane = tid & 63;
  const int w8 = tid >> 6;
  const int wr = w8 >> 2;                 // 0..1 row half
  const int wcol = w8 & 3;                // 0..3 col quarter

  f32x4 acc[8][4] = {};

  const int srow = tid >> 3;              // 0..63
  const int ksw = ((tid & 7) ^ (srow & 7)) * 8;
  const unsigned short* Ab = A + (size_t)(t0 + srow) * 8192 + ks * 4096 + ksw;
  const unsigned short* Bb = B + (size_t)(n0 + srow) * 8192 + ks * 4096 + ksw;

  const int l15 = lane & 15;
  const int krd = (lane >> 4) * 8;
  const int rsw = (lane & 7) << 3;
  const int e0 = (krd ^ rsw) * 2;
  const int e1 = ((32 + krd) ^ rsw) * 2;

#define ISS_A(buf, kt, j)                                                               \
  __builtin_amdgcn_global_load_lds(                                                    \
      (const __attribute__((address_space(1))) void*)(Ab + (kt) + (size_t)(j) * 64 * 8192), \
      (__attribute__((address_space(3))) void*)(&As[buf][(j) * 4096 + tid * 8]), 16, 0, 0);
#define ISS_B(buf, kt, j)                                                               \
  __builtin_amdgcn_global_load_lds(                                                    \
      (const __attribute__((address_space(1))) void*)(Bb + (kt) + (size_t)(j) * 64 * 8192), \
      (__attribute__((address_space(3))) void*)(&Bs[buf][(j) * 4096 + tid * 8]), 16, 0, 0);

#define MFMA16(IB)                                                                      \
  acc[IB+0][0] = __builtin_amdgcn_mfma_f32_16x16x32_bf16(af0, bf0, acc[IB+0][0], 0,0,0); \
  acc[IB+0][1] = __builtin_amdgcn_mfma_f32_16x16x32_bf16(af0, bf1, acc[IB+0][1], 0,0,0); \
  acc[IB+0][2] = __builtin_amdgcn_mfma_f32_16x16x32_bf16(af0, bf2, acc[IB+0][2], 0,0,0); \
  acc[IB+0][3] = __builtin_amdgcn_mfma_f32_16x16x32_bf16(af0, bf3, acc[IB+0][3], 0,0,0); \
  acc[IB+1][0] = __builtin_amdgcn_mfma_f32_16x16x32_bf16(af1, bf0, acc[IB+1][0], 0,0,0); \
  acc[IB+1][1] = __builtin_amdgcn_mfma_f32_16x16x32_bf16(af1, bf1, acc[IB+1][1], 0,0,0); \
  acc[IB+1][2] = __builtin_amdgcn_mfma_f32_16x16x32_bf16(af1, bf2, acc[IB+1][2], 0,0,0); \
  acc[IB+1][3] = __builtin_amdgcn_mfma_f32_16x16x32_bf16(af1, bf3, acc[IB+1][3], 0,0,0); \
  acc[IB+2][0] = __builtin_amdgcn_mfma_f32_16x16x32_bf16(af2, bf0, acc[IB+2][0], 0,0,0); \
  acc[IB+2][1] = __builtin_amdgcn_mfma_f32_16x16x32_bf16(af2, bf1, acc[IB+2][1], 0,0,0); \
  acc[IB+2][2] = __builtin_amdgcn_mfma_f32_16x16x32_bf16(af2, bf2, acc[IB+2][2], 0,0,0); \
  acc[IB+2][3] = __builtin_amdgcn_mfma_f32_16x16x32_bf16(af2, bf3, acc[IB+2][3], 0,0,0); \
  acc[IB+3][0] = __builtin_amdgcn_mfma_f32_16x16x32_bf16(af3, bf0, acc[IB+3][0], 0,0,0); \
  acc[IB+3][1] = __builtin_amdgcn_mfma_f32_16x16x32_bf16(af3, bf1, acc[IB+3][1], 0,0,0); \
  acc[IB+3][2] = __builtin_amdgcn_mfma_f32_16x16x32_bf16(af3, bf2, acc[IB+3][2], 0,0,0); \
  acc[IB+3][3] = __builtin_amdgcn_mfma_f32_16x16x32_bf16(af3, bf3, acc[IB+3][3], 0,0,0);

#define PHASE_TAIL                                                                      \
  __builtin_amdgcn_s_barrier();                                                         \
  asm volatile("s_waitcnt lgkmcnt(0)" ::: "memory");                                    \
  __builtin_amdgcn_sched_barrier(0);                                                    \
  __builtin_amdgcn_s_setprio(1);
#define PHASE_END                                                                       \
  __builtin_amdgcn_s_setprio(0);                                                        \
  __builtin_amdgcn_s_barrier();

  const int iters = 64;
  ISS_A(0, 0, 0) ISS_A(0, 0, 1) ISS_A(0, 0, 2) ISS_A(0, 0, 3)
  ISS_B(0, 0, 0) ISS_B(0, 0, 1) ISS_B(0, 0, 2) ISS_B(0, 0, 3)
  ISS_A(1, 64, 0) ISS_A(1, 64, 1) ISS_A(1, 64, 2) ISS_A(1, 64, 3)

  int abuf = 0;
  for (int t = 0; t < iters; ++t) {
    const int bbuf = t & 1;
    asm volatile("s_waitcnt vmcnt(4)" ::: "memory");
    __builtin_amdgcn_s_barrier();
    __builtin_amdgcn_sched_barrier(0);

    const char* Apb = (const char*)&As[abuf][(wr * 128 + l15) * 64];
    const char* Bpb = (const char*)&Bs[bbuf][(wcol * 64 + l15) * 64];
    const int tb = (t + 1 < iters) ? (t + 1) * 64 : t * 64;
    const int ta = (t + 2 < iters) ? (t + 2) * 64 : t * 64;
    const int nb = (t + 1) & 1;
    int na = abuf + 2; if (na >= 3) na -= 3;

    bf16x8 bf0, bf1, bf2, bf3, af0, af1, af2, af3;

    bf0 = *(const bf16x8*)(Bpb + e0);
    bf1 = *(const bf16x8*)(Bpb + 2048 + e0);
    bf2 = *(const bf16x8*)(Bpb + 4096 + e0);
    bf3 = *(const bf16x8*)(Bpb + 6144 + e0);
    af0 = *(const bf16x8*)(Apb + e0);
    af1 = *(const bf16x8*)(Apb + 2048 + e0);
    af2 = *(const bf16x8*)(Apb + 4096 + e0);
    af3 = *(const bf16x8*)(Apb + 6144 + e0);
    ISS_B(nb, tb, 0) ISS_B(nb, tb, 1)
    PHASE_TAIL
    MFMA16(0)
    PHASE_END

    af0 = *(const bf16x8*)(Apb + 8192 + e0);
    af1 = *(const bf16x8*)(Apb + 10240 + e0);
    af2 = *(const bf16x8*)(Apb + 12288 + e0);
    af3 = *(const bf16x8*)(Apb + 14336 + e0);
    ISS_B(nb, tb, 2) ISS_B(nb, tb, 3)
    PHASE_TAIL
    MFMA16(4)
    PHASE_END

    bf0 = *(const bf16x8*)(Bpb + e1);
    bf1 = *(const bf16x8*)(Bpb + 2048 + e1);
    bf2 = *(const bf16x8*)(Bpb + 4096 + e1);
    bf3 = *(const bf16x8*)(Bpb + 6144 + e1);
    af0 = *(const bf16x8*)(Apb + e1);
    af1 = *(const bf16x8*)(Apb + 2048 + e1);
    af2 = *(const bf16x8*)(Apb + 4096 + e1);
    af3 = *(const bf16x8*)(Apb + 6144 + e1);
    ISS_A(na, ta, 0) ISS_A(na, ta, 1)
    PHASE_TAIL
    MFMA16(0)
    PHASE_END

    af0 = *(const bf16x8*)(Apb + 8192 + e1);
    af1 = *(const bf16x8*)(Apb + 10240 + e1);
    af2 = *(const bf16x8*)(Apb + 12288 + e1);
    af3 = *(const bf16x8*)(Apb + 14336 + e1);
    ISS_A(na, ta, 2) ISS_A(na, ta, 3)
    PHASE_TAIL
    MFMA16(4)
    PHASE_END

    abuf += 1; if (abuf >= 3) abuf -= 3;
  }
  asm volatile("s_waitcnt vmcnt(0)" ::: "memory");

  float* Cp = partials + (size_t)ks * T_DIM * 1024;
  const int rbase = t0 + wr * 128 + ((lane >> 4) * 4);
  const int cbase = n0 + wcol * 64 + l15;
#pragma unroll
  for (int j = 0; j < 4; ++j) {
    const int col = cbase + j * 16;
#pragma unroll
    for (int i = 0; i < 8; ++i)
#pragma unroll
      for (int r = 0; r < 4; ++r)
        Cp[(size_t)(rbase + i * 16 + r) * 1024 + col] = acc[i][j][r];
  }
#undef ISS_A
#undef ISS_B
#undef MFMA16
#undef PHASE_TAIL
#undef PHASE_END
}

// ---------------- fallback split-K mix GEMM (m97 structure) ----------------
__global__ __launch_bounds__(256, 4) void gemm_splitk_kernel(
    const unsigned short* __restrict__ A, const unsigned short* __restrict__ B,
    float* __restrict__ partials, int nbm, int kslice, int prows) {
  __shared__ __align__(16) unsigned short As[128 * 64];
  __shared__ __align__(16) unsigned short Bs[128 * 64];
  const int cpx = gridDim.x >> 3;
  const int wid = (blockIdx.x & 7) * cpx + (blockIdx.x >> 3);
  const int bm = wid % nbm;
  const int bn = (wid / nbm) & 7;
  const int ks = wid / (nbm * 8);
  const int n0 = bn * 128, t0 = bm * 128;
  GEMM_PREAMBLE
  const unsigned short* Ab = A + (size_t)(t0 + srow) * 8192 + ks * kslice + ksw;
  const unsigned short* Bb = B + (size_t)(n0 + srow) * 8192 + ks * kslice + ksw;
  const int kloop_end = kslice;
  GEMM_KLOOP(Ab, Bb, 8192)

  float* Cp = partials + (size_t)ks * prows * 1024;
  const int rbase = t0 + wr * 64 + ((lane >> 4) * 4);
  const int cbase = n0 + wc * 64 + l15;
#pragma unroll
  for (int j = 0; j < 4; ++j) {
    const int col = cbase + j * 16;
#pragma unroll
    for (int i = 0; i < 4; ++i)
#pragma unroll
      for (int r = 0; r < 4; ++r)
        Cp[(size_t)(rbase + i * 16 + r) * 1024 + col] = acc[i][j][r];
  }
}

// fallback reduce
__global__ __launch_bounds__(256) void reduce_kernel(const f32x4* __restrict__ partials,
                                                     const f32x4* __restrict__ bias4,
                                                     f32x4* __restrict__ outc) {
  int i = blockIdx.x * 256 + threadIdx.x;
  const size_t stride = (size_t)CHUNK * 256;
  f32x4 s = partials[i];
#pragma unroll
  for (int p = 1; p < KS_FB; ++p) s += partials[(size_t)p * stride + i];
  s += bias4[i & 255];
  outc[i] = s;
}

// ---------------- gated_x = pre * sigmoid(gin) ----------------
__global__ __launch_bounds__(256) void gated_kernel(const float* __restrict__ tmp,
                                                    float* __restrict__ gated) {
  int i = blockIdx.x * 256 + threadIdx.x;
  int t = i >> 7, m = i & 127;
  float p = tmp[t * 256 + m];
  float g = tmp[t * 256 + 128 + m];
  gated[i] = p * sigm(g);
}

// ================= parallel scan =================
__global__ __launch_bounds__(256) void scan_p1_kernel(
    const float* __restrict__ gated, const int* __restrict__ done,
    const float2* __restrict__ gam, const float2* __restrict__ gamL,
    float2* __restrict__ carryA, float2* __restrict__ carryB) {
  int gid = blockIdx.x * 256 + threadIdx.x;
  int seg = gid >> 12, tid = gid & 4095;
  int m = tid >> 5;
  float2 g = gam[tid];
  int t0 = seg * SEG;
  float sr = 0.f, si = 0.f, keep_all = 1.f;
  for (int tt = 0; tt < SEG; ++tt) {
    int t = t0 + tt;
    float xv = gated[t * M_DIM + m];
    bool d = done[t] != 0;
    float pr = d ? 0.f : sr;
    float pi = d ? 0.f : si;
    if (d) keep_all = 0.f;
    sr = fmaf(g.x, pr, fmaf(-g.y, pi, xv));
    si = fmaf(g.y, pr, g.x * pi);
  }
  carryB[(size_t)seg * 4096 + tid] = make_float2(sr, si);
  float2 gL = gamL[tid];
  carryA[(size_t)seg * 4096 + tid] = make_float2(keep_all * gL.x, keep_all * gL.y);
}

__global__ __launch_bounds__(256) void scan_p2_kernel(
    const float2* __restrict__ carryA, float2* __restrict__ carryB,
    const float* __restrict__ s0_re, const float* __restrict__ s0_im) {
  int tid = blockIdx.x * 256 + threadIdx.x;
  float sr = s0_re[tid], si = s0_im[tid];
  float2 A0 = carryA[tid], B0 = carryB[tid];
  for (int p = 0; p < NSEG; ++p) {
    size_t nidx = (size_t)(p + 1) * 4096 + tid;
    float2 A1, B1;
    if (p + 1 < NSEG) { A1 = carryA[nidx]; B1 = carryB[nidx]; }
    carryB[(size_t)p * 4096 + tid] = make_float2(sr, si);
    float nr = fmaf(A0.x, sr, fmaf(-A0.y, si, B0.x));
    float ni = fmaf(A0.y, sr, fmaf(A0.x, si, B0.y));
    sr = nr; si = ni;
    A0 = A1; B0 = B1;
  }
}

__global__ __launch_bounds__(256) void scan_p3_kernel(
    const float* __restrict__ gated, const int* __restrict__ done,
    const float2* __restrict__ gam, const float2* __restrict__ segstart,
    float* __restrict__ out_states, int pair_mode,
    unsigned int* __restrict__ st_bf, int tbase) {
  int gid = blockIdx.x * 256 + threadIdx.x;
  int segl = gid >> 12, tid = gid & 4095;
  int m = tid >> 5;
  int seg = tbase / SEG + segl;
  float2 g = gam[tid];
  float2 s = segstart[(size_t)seg * 4096 + tid];
  float sr = s.x, si = s.y;
  int t0 = seg * SEG;
  for (int tt = 0; tt < SEG; ++tt) {
    int t = t0 + tt;
    float xv = gated[t * M_DIM + m];
    bool d = done[t] != 0;
    float pr = d ? 0.f : sr;
    float pi = d ? 0.f : si;
    sr = fmaf(g.x, pr, fmaf(-g.y, pi, xv));
    si = fmaf(g.y, pr, g.x * pi);
    if (pair_mode) {
      ((float2*)out_states)[(size_t)t * 4096 + tid] = make_float2(sr, si);
    } else {
      out_states[(size_t)t * 4096 + tid] = sr;
    }
    st_bf[(size_t)(t - tbase) * 4096 + tid] =
        (unsigned int)f2bf(sr) | ((unsigned int)f2bf(si) << 16);
  }
}

// ---------------- fused reduce + bias + LN + gates ----------------
__global__ __launch_bounds__(256) void ln_kernel(const float* __restrict__ partials, int nred,
                                                 const float* __restrict__ mixb,
                                                 const unsigned short* __restrict__ gs,
                                                 float* __restrict__ out) {
  const int t = blockIdx.x;
  const int tid = threadIdx.x;
  __shared__ float sm[8];
  const int o = tid * 4;
  f32x4 z;
  if (nred == 0) {
    z = *(const f32x4*)&out[(size_t)t * 1024 + o];
  } else {
    z = *(const f32x4*)&partials[(size_t)t * 1024 + o];
    for (int p = 1; p < nred; ++p)
      z += *(const f32x4*)&partials[(size_t)p * T_DIM * 1024 + (size_t)t * 1024 + o];
    z += *(const f32x4*)&mixb[o];
  }
  ushort4 gu = *(const ushort4*)&gs[(size_t)t * 2048 + o];
  ushort4 su = *(const ushort4*)&gs[(size_t)t * 2048 + 1024 + o];
  float g[4], sk[4], zg[4];
  g[0] = sigm(bf2f(gu.x)); g[1] = sigm(bf2f(gu.y));
  g[2] = sigm(bf2f(gu.z)); g[3] = sigm(bf2f(gu.w));
  sk[0] = bf2f(su.x); sk[1] = bf2f(su.y); sk[2] = bf2f(su.z); sk[3] = bf2f(su.w);
  float sum = 0.f;
#pragma unroll
  for (int j = 0; j < 4; ++j) { zg[j] = z[j] * g[j]; sum += zg[j]; }
#pragma unroll
  for (int off = 32; off > 0; off >>= 1) sum += __shfl_down(sum, off, 64);
  if ((tid & 63) == 0) sm[tid >> 6] = sum;
  __syncthreads();
  const float mu = (sm[0] + sm[1] + sm[2] + sm[3]) * (1.f / 1024.f);
  float sq = 0.f;
#pragma unroll
  for (int j = 0; j < 4; ++j) { float d = zg[j] - mu; sq += d * d; }
#pragma unroll
  for (int off = 32; off > 0; off >>= 1) sq += __shfl_down(sq, off, 64);
  if ((tid & 63) == 0) sm[4 + (tid >> 6)] = sq;
  __syncthreads();
  const float var = (sm[4] + sm[5] + sm[6] + sm[7]) * (1.f / 1024.f);
  const float rstd = 1.f / sqrtf(var + 1e-5f);
  f32x4 res;
#pragma unroll
  for (int j = 0; j < 4; ++j) res[j] = (zg[j] - mu) * rstd + sk[j] * (1.f - g[j]);
  *(f32x4*)&out[(size_t)t * 1024 + o] = res;
}

extern "C" void kernel_launch(void* const* d_in, const int* in_sizes, int n_in,
                              void* d_out, int out_size, void* d_ws, size_t ws_size,
                              hipStream_t stream) {
  const float* x      = (const float*)d_in[0];
  const int*   done   = (const int*)d_in[1];
  const float* s0_re  = (const float*)d_in[2];
  const float* s0_im  = (const float*)d_in[3];
  const float* a      = (const float*)d_in[4];
  const float* b      = (const float*)d_in[5];
  const float* pre_w  = (const float*)d_in[6];
  const float* pre_b  = (const float*)d_in[7];
  const float* gin_w  = (const float*)d_in[8];
  const float* gin_b  = (const float*)d_in[9];
  const float* gout_w = (const float*)d_in[10];
  const float* gout_b = (const float*)d_in[11];
  const float* skip_w = (const float*)d_in[12];
  const float* skip_b = (const float*)d_in[13];
  const float* mix_w  = (const float*)d_in[14];
  const float* mix_b  = (const float*)d_in[15];

  float* out_f = (float*)d_out;                               // [T][1024]
  float* states_f = out_f + (size_t)T_DIM * OUT_DIM;
  const int pair_mode = (out_size >= 75000000) ? 1 : 0;

  char* ws = (char*)d_ws;
  size_t off = 0;
  auto alloc = [&](size_t bytes) {
    void* p = ws + off;
    off = (off + bytes + 255) & ~(size_t)255;
    return p;
  };
  unsigned short* x_bf   = (unsigned short*)alloc((size_t)T_DIM * IN_DIM * 2);
  unsigned short* Bmix   = (unsigned short*)alloc((size_t)OUT_DIM * 8192 * 2);
  unsigned short* Wgs    = (unsigned short*)alloc((size_t)2304 * IN_DIM * 2);
  float* bias_gs         = (float*)alloc(2304 * 4);
  float* tmp_pg          = (float*)alloc((size_t)T_DIM * 256 * 4);
  float* gated           = (float*)alloc((size_t)T_DIM * M_DIM * 4);
  float2* gam            = (float2*)alloc(4096 * 8);
  float2* gamL           = (float2*)alloc(4096 * 8);
  float2* carryA         = (float2*)alloc((size_t)NSEG * 4096 * 8);
  float2* carryB         = (float2*)alloc((size_t)NSEG * 4096 * 8);
  unsigned short* gs_o   = (unsigned short*)alloc((size_t)T_DIM * 2048 * 2);

  size_t need_main = off + (size_t)T_DIM * 8192 * 2 + (size_t)2 * T_DIM * 1024 * 4 + 1024;
  const int full_path = (ws_size == 0 || ws_size >= need_main) ? 1 : 0;

  dim3 blk(256);
  prep_kernel<<<2048, blk, 0, stream>>>(x, mix_w, gout_w, skip_w, pre_w, gin_w,
                                        gout_b, skip_b, pre_b, gin_b, a, b,
                                        x_bf, Bmix, Wgs, bias_gs, gam, gamL);

  gemm_gs_kernel<<<1152, blk, 0, stream>>>(x_bf, Wgs, bias_gs, gs_o, tmp_pg);
  gated_kernel<<<(T_DIM * M_DIM) / 256, blk, 0, stream>>>(tmp_pg, gated);

  scan_p1_kernel<<<NSEG * 16, blk, 0, stream>>>(gated, done, gam, gamL, carryA, carryB);
  scan_p2_kernel<<<16, blk, 0, stream>>>(carryA, carryB, s0_re, s0_im);

  if (full_path) {
    unsigned short* st_bf = (unsigned short*)alloc((size_t)T_DIM * 8192 * 2);
    float* partials       = (float*)alloc((size_t)2 * T_DIM * 1024 * 4);
    scan_p3_kernel<<<NSEG * 16, blk, 0, stream>>>(gated, done, gam, carryB,
                                                  states_f, pair_mode,
                                                  (unsigned int*)st_bf, 0);
    // fine 8-phase 256x256 split-K GEMM: 256 blocks = 1/CU, 8 waves each
    gemm_mix256_kernel<<<256, dim3(512), 0, stream>>>(st_bf, Bmix, partials);
    ln_kernel<<<T_DIM, blk, 0, stream>>>(partials, 2, mix_b, gs_o, out_f);
  } else {
    unsigned short* st_bf = (unsigned short*)alloc((size_t)CHUNK * 8192 * 2);
    float* partials       = (float*)alloc((size_t)KS_FB * CHUNK * 1024 * 4);
    for (int ch = 0; ch < T_DIM / CHUNK; ++ch) {
      int tbase = ch * CHUNK;
      scan_p3_kernel<<<(CHUNK / SEG) * 16, blk, 0, stream>>>(gated, done, gam, carryB,
                                                             states_f, pair_mode,
                                                             (unsigned int*)st_bf, tbase);
      gemm_splitk_kernel<<<8 * (CHUNK / 128) * KS_FB, blk, 0, stream>>>(
          st_bf, Bmix, partials, CHUNK / 128, 8192 / KS_FB, CHUNK);
      reduce_kernel<<<CHUNK, blk, 0, stream>>>((const f32x4*)partials, (const f32x4*)mix_b,
                                               (f32x4*)(out_f + (size_t)tbase * OUT_DIM));
    }
    ln_kernel<<<T_DIM, blk, 0, stream>>>(nullptr, 0, mix_b, gs_o, out_f);
  }
  (void)n_in; (void)in_sizes;
}